// Round 1
// baseline (229.367 us; speedup 1.0000x reference)
//
#include <hip/hip_runtime.h>
#include <math.h>

// CopyMamba3LM restructured by token-id factorization:
//  h/q/k/gate/vocab_probs depend only on token id (256 values) ->
//  scores[b,t,s] = S256[tok[t],tok[s]]/ref-scale; softmax denominator needs
//  only per-batch token histogram cnt[b][v]. attn + log(mixed) become
//  gathers from 8x256x256 tables. Output is ~151 MB of stores (write-bound).

#define DM 512
#define VC 256
#define SL 2048
#define NB 8
#define AD 64

__device__ __forceinline__ float wave_sum(float v) {
#pragma unroll
  for (int o = 32; o > 0; o >>= 1) v += __shfl_xor(v, o, 64);
  return v;
}
__device__ __forceinline__ float wave_max(float v) {
#pragma unroll
  for (int o = 32; o > 0; o >>= 1) v = fmaxf(v, __shfl_xor(v, o, 64));
  return v;
}
// block = 256 threads = 4 waves
__device__ __forceinline__ float blk_sum(float v, float* red) {
  v = wave_sum(v);
  if ((threadIdx.x & 63) == 0) red[threadIdx.x >> 6] = v;
  __syncthreads();
  float r = red[0] + red[1] + red[2] + red[3];
  __syncthreads();
  return r;
}
__device__ __forceinline__ float blk_max(float v, float* red) {
  v = wave_max(v);
  if ((threadIdx.x & 63) == 0) red[threadIdx.x >> 6] = v;
  __syncthreads();
  float r = fmaxf(fmaxf(red[0], red[1]), fmaxf(red[2], red[3]));
  __syncthreads();
  return r;
}

// Per-token precompute: h = LN(LN(embed[tt])), q/k rows, gate, vocab softmax.
__global__ __launch_bounds__(256) void ktok_pre(
    const float* __restrict__ embed_w,
    const float* __restrict__ en_g, const float* __restrict__ en_b,
    const float* __restrict__ fn_g, const float* __restrict__ fn_b,
    const float* __restrict__ q_w, const float* __restrict__ q_b,
    const float* __restrict__ k_w, const float* __restrict__ k_b,
    const float* __restrict__ g_w, const float* __restrict__ g_b,
    float* __restrict__ h_tok, float* __restrict__ q_tok,
    float* __restrict__ k_tok, float* __restrict__ gate_tok,
    float* __restrict__ probs_tok)
{
  __shared__ float red[4];
  __shared__ float hs[DM];
  const int tt = blockIdx.x;    // token id 0..255
  const int tid = threadIdx.x;  // 0..255, each owns elems tid and tid+256

  float x0 = embed_w[tt * DM + tid];
  float x1 = embed_w[tt * DM + 256 + tid];
  // LN 1 (embed_norm)
  float mu = blk_sum(x0 + x1, red) * (1.0f / DM);
  float d0 = x0 - mu, d1 = x1 - mu;
  float var = blk_sum(d0 * d0 + d1 * d1, red) * (1.0f / DM);
  float inv = 1.0f / sqrtf(var + 1e-5f);
  float y0 = d0 * inv * en_g[tid] + en_b[tid];
  float y1 = d1 * inv * en_g[tid + 256] + en_b[tid + 256];
  // LN 2 (final_norm)
  mu = blk_sum(y0 + y1, red) * (1.0f / DM);
  d0 = y0 - mu; d1 = y1 - mu;
  var = blk_sum(d0 * d0 + d1 * d1, red) * (1.0f / DM);
  inv = 1.0f / sqrtf(var + 1e-5f);
  float h0 = d0 * inv * fn_g[tid] + fn_b[tid];
  float h1 = d1 * inv * fn_g[tid + 256] + fn_b[tid + 256];
  hs[tid] = h0; hs[tid + 256] = h1;
  h_tok[tt * DM + tid] = h0;
  h_tok[tt * DM + 256 + tid] = h1;
  // gate = sigmoid(h . g_w + g_b)   (blk_sum's barrier also publishes hs[])
  float gp = blk_sum(h0 * g_w[tid] + h1 * g_w[tid + 256], red);
  if (tid == 0) gate_tok[tt] = 1.0f / (1.0f + expf(-(gp + g_b[0])));
  // q, k rows: threads 0..63 -> q, 64..127 -> k
  if (tid < 128) {
    int a = tid & 63;
    const float* w = (tid < 64 ? q_w : k_w) + a * DM;
    float acc = 0.0f;
    for (int d = 0; d < DM; ++d) acc += hs[d] * w[d];
    if (tid < 64) q_tok[tt * AD + a] = acc + q_b[a];
    else          k_tok[tt * AD + a] = acc + k_b[a];
  }
  // tied vocab head + softmax: thread tid = vocab v
  const float* ev = embed_w + tid * DM;
  float logit = 0.0f;
  for (int d = 0; d < DM; ++d) logit += hs[d] * ev[d];
  float m = blk_max(logit, red);
  float e = expf(logit - m);
  float Z = blk_sum(e, red);
  probs_tok[tt * VC + tid] = e / Z;
}

// S256[tt][ts] = (q_tok[tt] . k_tok[ts]) / sqrt(64)
__global__ __launch_bounds__(256) void kscores(
    const float* __restrict__ q_tok, const float* __restrict__ k_tok,
    float* __restrict__ S)
{
  __shared__ float qr[AD];
  int tt = blockIdx.x, tid = threadIdx.x;
  if (tid < AD) qr[tid] = q_tok[tt * AD + tid];
  __syncthreads();
  const float* kr = k_tok + tid * AD;
  float acc = 0.0f;
#pragma unroll
  for (int a = 0; a < AD; ++a) acc += qr[a] * kr[a];
  S[tt * VC + tid] = acc * 0.125f;
}

// Per-batch token histogram over the prefix (mask = s < P && tok != PAD)
__global__ __launch_bounds__(256) void khist(
    const int* __restrict__ tokens, const int* __restrict__ prefix_lens,
    int* __restrict__ cnt)
{
  __shared__ int c[VC];
  int b = blockIdx.x, tid = threadIdx.x;
  c[tid] = 0;
  __syncthreads();
  int P = prefix_lens[b];
  for (int s = tid; s < SL; s += 256) {
    if (s < P) {
      int t = tokens[b * SL + s];
      if (t != 0) atomicAdd(&c[t], 1);
    }
  }
  __syncthreads();
  cnt[b * VC + tid] = c[tid];
}

// Per (b, token) softmax tables: e_norm[b][tt][v] and log(mixed)[b][tt][v]
__global__ __launch_bounds__(256) void ktables(
    const float* __restrict__ S, const int* __restrict__ cnt,
    const float* __restrict__ gate_tok, const float* __restrict__ probs_tok,
    float* __restrict__ e_norm, float* __restrict__ logmix)
{
  __shared__ float red[4];
  int b = blockIdx.x >> 8, tt = blockIdx.x & 255;
  int v = threadIdx.x;
  float sv = S[tt * VC + v];
  int c = cnt[b * VC + v];
  float m = blk_max(c > 0 ? sv : -1e30f, red);  // max over unmasked keys
  float e = expf(sv - m);
  float Z = blk_sum((float)c * e, red);
  float en = e / Z;
  int idx = (b * VC + tt) * VC + v;
  e_norm[idx] = en;
  float g = gate_tok[tt];
  float mixed = g * probs_tok[tt * VC + v] + (1.0f - g) * ((float)c * en);
  logmix[idx] = logf(fmaxf(mixed, 1e-12f));
}

// Output writer: one block per (b,t) row. ~151 MB of stores total.
__global__ __launch_bounds__(256) void kwrite(
    const int* __restrict__ tokens, const int* __restrict__ prefix_lens,
    const float* __restrict__ e_norm, const float* __restrict__ logmix,
    const float* __restrict__ gate_tok,
    float* __restrict__ out_logmix, float* __restrict__ out_gate,
    float* __restrict__ out_attn)
{
  __shared__ float erow[VC];
  int row = blockIdx.x;          // b*SL + t
  int b = row >> 11;
  int tid = threadIdx.x;
  int tt = tokens[row];
  int base = (b * VC + tt) * VC;
  erow[tid] = e_norm[base + tid];
  out_logmix[(size_t)row * VC + tid] = logmix[base + tid];
  if (tid == 0) out_gate[row] = gate_tok[tt];
  int P = prefix_lens[b];
  __syncthreads();
  const int4* tokrow = (const int4*)(tokens + b * SL);
  float4* arow = (float4*)(out_attn + (size_t)row * SL);
  for (int i = tid; i < SL / 4; i += 256) {
    int4 tk = tokrow[i];
    int s0 = i * 4;
    float4 val;
    val.x = (s0     < P && tk.x != 0) ? erow[tk.x] : 0.0f;
    val.y = (s0 + 1 < P && tk.y != 0) ? erow[tk.y] : 0.0f;
    val.z = (s0 + 2 < P && tk.z != 0) ? erow[tk.z] : 0.0f;
    val.w = (s0 + 3 < P && tk.w != 0) ? erow[tk.w] : 0.0f;
    arow[i] = val;
  }
}

extern "C" void kernel_launch(void* const* d_in, const int* in_sizes, int n_in,
                              void* d_out, int out_size, void* d_ws, size_t ws_size,
                              hipStream_t stream)
{
  const int*   tokens      = (const int*)  d_in[0];
  const int*   prefix_lens = (const int*)  d_in[1];
  const float* embed_w     = (const float*)d_in[2];
  const float* en_g        = (const float*)d_in[3];
  const float* en_b        = (const float*)d_in[4];
  const float* fn_g        = (const float*)d_in[5];
  const float* fn_b        = (const float*)d_in[6];
  const float* q_w         = (const float*)d_in[7];
  const float* q_b         = (const float*)d_in[8];
  const float* k_w         = (const float*)d_in[9];
  const float* k_b         = (const float*)d_in[10];
  const float* g_w         = (const float*)d_in[11];
  const float* g_b         = (const float*)d_in[12];

  // workspace layout (floats): ~5.4 MB total
  float* ws        = (float*)d_ws;
  float* h_tok     = ws;                       // 256*512
  float* q_tok     = h_tok + 256 * 512;        // 256*64
  float* k_tok     = q_tok + 256 * 64;         // 256*64
  float* gate_tok  = k_tok + 256 * 64;         // 256
  float* probs_tok = gate_tok + 256;           // 256*256
  float* S         = probs_tok + 256 * 256;    // 256*256
  int*   cnt       = (int*)(S + 256 * 256);    // 8*256
  float* e_norm    = (float*)(cnt + 8 * 256);  // 8*256*256
  float* logmix    = e_norm + 8 * 256 * 256;   // 8*256*256

  float* out_logmix = (float*)d_out;                      // 8*2048*256
  float* out_gate   = out_logmix + (size_t)NB * SL * VC;  // 8*2048
  float* out_attn   = out_gate + (size_t)NB * SL;         // 8*2048*2048

  ktok_pre<<<256, 256, 0, stream>>>(embed_w, en_g, en_b, fn_g, fn_b,
      q_w, q_b, k_w, k_b, g_w, g_b, h_tok, q_tok, k_tok, gate_tok, probs_tok);
  kscores<<<256, 256, 0, stream>>>(q_tok, k_tok, S);
  khist<<<NB, 256, 0, stream>>>(tokens, prefix_lens, cnt);
  ktables<<<NB * 256, 256, 0, stream>>>(S, cnt, gate_tok, probs_tok, e_norm, logmix);
  kwrite<<<NB * SL, 256, 0, stream>>>(tokens, prefix_lens, e_norm, logmix,
      gate_tok, out_logmix, out_gate, out_attn);
}

// Round 2
// 217.888 us; speedup vs baseline: 1.0527x; 1.0527x over previous
//
#include <hip/hip_runtime.h>
#include <math.h>

// CopyMamba3LM, token-id factorization (round 2).
// R1 lesson: per-lane row-walk dot products (lane i reads w[i*512+d]) touch
// 64 cache lines per wave-load -> ktok_pre dominated at ~100 us. Fix: pack
// transposed, d-major operands once (coalesced dwordx4 across lanes), fold
// kernels 5 -> 4. Output kernel is write-bound: ~151 MB stores ~= 24 us floor.

#define DM 512
#define VC 256
#define SL 2048
#define NB 8
#define AD 64

typedef float f4v __attribute__((ext_vector_type(4)));

__device__ __forceinline__ float wave_sum(float v) {
#pragma unroll
  for (int o = 32; o > 0; o >>= 1) v += __shfl_xor(v, o, 64);
  return v;
}
__device__ __forceinline__ float wave_max(float v) {
#pragma unroll
  for (int o = 32; o > 0; o >>= 1) v = fmaxf(v, __shfl_xor(v, o, 64));
  return v;
}
// block = 256 threads = 4 waves
__device__ __forceinline__ float blk_sum(float v, float* red) {
  v = wave_sum(v);
  if ((threadIdx.x & 63) == 0) red[threadIdx.x >> 6] = v;
  __syncthreads();
  float r = red[0] + red[1] + red[2] + red[3];
  __syncthreads();
  return r;
}
__device__ __forceinline__ float blk_max(float v, float* red) {
  v = wave_max(v);
  if ((threadIdx.x & 63) == 0) red[threadIdx.x >> 6] = v;
  __syncthreads();
  float r = fmaxf(fmaxf(red[0], red[1]), fmaxf(red[2], red[3]));
  __syncthreads();
  return r;
}

// K1: pack transposed operands + per-batch token histogram.
// blocks 0..511: d = blockIdx -> embed_P[((d/4)*256+v)*4 + d%4] etc.
// blocks 512..519: histogram for batch blockIdx-512.
__global__ __launch_bounds__(256) void kprep(
    const float* __restrict__ embed_w, const float* __restrict__ q_w,
    const float* __restrict__ k_w, const int* __restrict__ tokens,
    const int* __restrict__ prefix_lens,
    float* __restrict__ embed_P, float* __restrict__ qk_P,
    int* __restrict__ cnt)
{
  __shared__ int c[VC];
  const int blk = blockIdx.x;
  const int tid = threadIdx.x;
  if (blk < DM) {
    const int d = blk;
    embed_P[(((d >> 2) * VC + tid) << 2) + (d & 3)] = embed_w[tid * DM + d];
    if (tid < 128) {
      float val = (tid < 64) ? q_w[tid * DM + d] : k_w[(tid - 64) * DM + d];
      qk_P[(((d >> 2) * 128 + tid) << 2) + (d & 3)] = val;
    }
  } else {
    const int b = blk - DM;
    c[tid] = 0;
    __syncthreads();
    const int P = prefix_lens[b];
    for (int s = tid; s < SL; s += 256) {
      if (s < P) {
        int t = tokens[b * SL + s];
        if (t != 0) atomicAdd(&c[t], 1);
      }
    }
    __syncthreads();
    cnt[b * VC + tid] = c[tid];
  }
}

// K2: per-token h = LN(LN(embed[tt])), gate, q row, k row (written transposed
// packed), vocab logits + softmax. All inner loads coalesced dwordx4.
__global__ __launch_bounds__(256) void ktok(
    const float* __restrict__ embed_w,
    const float* __restrict__ en_g, const float* __restrict__ en_b,
    const float* __restrict__ fn_g, const float* __restrict__ fn_b,
    const float* __restrict__ q_b, const float* __restrict__ k_b,
    const float* __restrict__ g_w, const float* __restrict__ g_b,
    const float* __restrict__ embed_P, const float* __restrict__ qk_P,
    float* __restrict__ q_tok, float* __restrict__ kT_P,
    float* __restrict__ gate_tok, float* __restrict__ probs_tok)
{
  __shared__ float red[4];
  __shared__ __align__(16) float hs[DM];
  const int tt = blockIdx.x;    // token id
  const int tid = threadIdx.x;  // owns dims tid, tid+256

  float x0 = embed_w[tt * DM + tid];
  float x1 = embed_w[tt * DM + 256 + tid];
  // LN 1 (embed_norm)
  float mu = blk_sum(x0 + x1, red) * (1.0f / DM);
  float d0 = x0 - mu, d1 = x1 - mu;
  float var = blk_sum(d0 * d0 + d1 * d1, red) * (1.0f / DM);
  float inv = 1.0f / sqrtf(var + 1e-5f);
  float y0 = d0 * inv * en_g[tid] + en_b[tid];
  float y1 = d1 * inv * en_g[tid + 256] + en_b[tid + 256];
  // LN 2 (final_norm)
  mu = blk_sum(y0 + y1, red) * (1.0f / DM);
  d0 = y0 - mu; d1 = y1 - mu;
  var = blk_sum(d0 * d0 + d1 * d1, red) * (1.0f / DM);
  inv = 1.0f / sqrtf(var + 1e-5f);
  float h0 = d0 * inv * fn_g[tid] + fn_b[tid];
  float h1 = d1 * inv * fn_g[tid + 256] + fn_b[tid + 256];
  hs[tid] = h0; hs[tid + 256] = h1;
  // gate (blk_sum's barrier also publishes hs[])
  float gp = blk_sum(h0 * g_w[tid] + h1 * g_w[tid + 256], red);
  if (tid == 0) gate_tok[tt] = 1.0f / (1.0f + expf(-(gp + g_b[0])));

  const float4* hs4 = (const float4*)hs;
  // q/k rows: threads 0..127, coalesced reads of packed qk_P
  if (tid < 128) {
    const float4* w4p = (const float4*)qk_P;
    float acc = 0.0f;
#pragma unroll 8
    for (int d4 = 0; d4 < DM / 4; ++d4) {
      float4 h4 = hs4[d4];
      float4 w4 = w4p[d4 * 128 + tid];
      acc += h4.x * w4.x + h4.y * w4.y + h4.z * w4.z + h4.w * w4.w;
    }
    if (tid < 64) {
      q_tok[tt * AD + tid] = acc + q_b[tid];
    } else {
      int a = tid - 64;
      kT_P[(((a >> 2) * VC + tt) << 2) + (a & 3)] = acc + k_b[a];
    }
  }
  // tied vocab head + softmax: thread tid = vocab v, coalesced embed_P reads
  const float4* e4p = (const float4*)embed_P;
  float lt = 0.0f;
#pragma unroll 8
  for (int d4 = 0; d4 < DM / 4; ++d4) {
    float4 h4 = hs4[d4];
    float4 e4 = e4p[d4 * VC + tid];
    lt += h4.x * e4.x + h4.y * e4.y + h4.z * e4.z + h4.w * e4.w;
  }
  float m = blk_max(lt, red);
  float e = expf(lt - m);
  float Z = blk_sum(e, red);
  probs_tok[tt * VC + tid] = e / Z;
}

// K3: per (b, token-id) masked softmax tables (scores recomputed coalesced
// from packed k^T): e_norm[b][tt][v], logmix[b][tt][v].
__global__ __launch_bounds__(256) void ktables(
    const float* __restrict__ q_tok, const float* __restrict__ kT_P,
    const int* __restrict__ cnt, const float* __restrict__ gate_tok,
    const float* __restrict__ probs_tok,
    float* __restrict__ e_norm, float* __restrict__ logmix)
{
  __shared__ float red[4];
  __shared__ __align__(16) float qs[AD];
  const int b = blockIdx.x >> 8, tt = blockIdx.x & 255;
  const int v = threadIdx.x;
  if (v < AD) qs[v] = q_tok[tt * AD + v];
  __syncthreads();
  const float4* qs4 = (const float4*)qs;
  const float4* k4p = (const float4*)kT_P;
  float sv = 0.0f;
#pragma unroll
  for (int a4 = 0; a4 < AD / 4; ++a4) {
    float4 q4 = qs4[a4];
    float4 k4 = k4p[a4 * VC + v];
    sv += q4.x * k4.x + q4.y * k4.y + q4.z * k4.z + q4.w * k4.w;
  }
  sv *= 0.125f;  // 1/sqrt(64)
  int c = cnt[b * VC + v];
  float m = blk_max(c > 0 ? sv : -1e30f, red);  // max over unmasked keys
  float e = expf(sv - m);
  float Z = blk_sum((float)c * e, red);
  float en = e / Z;
  int idx = (b * VC + tt) * VC + v;
  e_norm[idx] = en;
  float g = gate_tok[tt];
  float mixed = g * probs_tok[tt * VC + v] + (1.0f - g) * ((float)c * en);
  logmix[idx] = logf(fmaxf(mixed, 1e-12f));
}

// K4: output writer — one block per (b,t) row; ~151 MB of stores.
__global__ __launch_bounds__(256) void kwrite(
    const int* __restrict__ tokens, const int* __restrict__ prefix_lens,
    const float* __restrict__ e_norm, const float* __restrict__ logmix,
    const float* __restrict__ gate_tok,
    float* __restrict__ out_logmix, float* __restrict__ out_gate,
    float* __restrict__ out_attn)
{
  __shared__ float erow[VC];
  const int row = blockIdx.x;  // b*SL + t
  const int b = row >> 11;
  const int tid = threadIdx.x;
  const int tt = tokens[row];
  const int base = (b * VC + tt) * VC;
  erow[tid] = e_norm[base + tid];
  out_logmix[(size_t)row * VC + tid] = logmix[base + tid];
  if (tid == 0) out_gate[row] = gate_tok[tt];
  const int P = prefix_lens[b];
  __syncthreads();
  const int4* tokrow = (const int4*)(tokens + b * SL);
  f4v* arow = (f4v*)(out_attn + (size_t)row * SL);
#pragma unroll
  for (int it = 0; it < 2; ++it) {
    int i = tid + it * 256;
    int4 tk = tokrow[i];
    int s0 = i * 4;
    f4v val;
    val.x = (s0     < P && tk.x != 0) ? erow[tk.x] : 0.0f;
    val.y = (s0 + 1 < P && tk.y != 0) ? erow[tk.y] : 0.0f;
    val.z = (s0 + 2 < P && tk.z != 0) ? erow[tk.z] : 0.0f;
    val.w = (s0 + 3 < P && tk.w != 0) ? erow[tk.w] : 0.0f;
    __builtin_nontemporal_store(val, &arow[i]);
  }
}

extern "C" void kernel_launch(void* const* d_in, const int* in_sizes, int n_in,
                              void* d_out, int out_size, void* d_ws, size_t ws_size,
                              hipStream_t stream)
{
  const int*   tokens      = (const int*)  d_in[0];
  const int*   prefix_lens = (const int*)  d_in[1];
  const float* embed_w     = (const float*)d_in[2];
  const float* en_g        = (const float*)d_in[3];
  const float* en_b        = (const float*)d_in[4];
  const float* fn_g        = (const float*)d_in[5];
  const float* fn_b        = (const float*)d_in[6];
  const float* q_b         = (const float*)d_in[8];
  const float* k_b         = (const float*)d_in[10];
  const float* q_w         = (const float*)d_in[7];
  const float* k_w         = (const float*)d_in[9];
  const float* g_w         = (const float*)d_in[11];
  const float* g_b         = (const float*)d_in[12];

  // workspace layout (floats), all 16B-aligned offsets; ~5.4 MB total
  float* ws        = (float*)d_ws;
  float* embed_P   = ws;                        // 512*256 packed transpose
  float* qk_P      = embed_P + DM * VC;         // 512*128
  float* kT_P      = qk_P + DM * 128;           // 64*256
  float* q_tok     = kT_P + AD * VC;            // 256*64
  float* gate_tok  = q_tok + VC * AD;           // 256
  float* probs_tok = gate_tok + VC;             // 256*256
  int*   cnt       = (int*)(probs_tok + VC * VC);  // 8*256
  float* e_norm    = (float*)(cnt + NB * VC);   // 8*256*256
  float* logmix    = e_norm + NB * VC * VC;     // 8*256*256

  float* out_logmix = (float*)d_out;                      // 8*2048*256
  float* out_gate   = out_logmix + (size_t)NB * SL * VC;  // 8*2048
  float* out_attn   = out_gate + (size_t)NB * SL;         // 8*2048*2048

  kprep<<<DM + NB, 256, 0, stream>>>(embed_w, q_w, k_w, tokens, prefix_lens,
                                     embed_P, qk_P, cnt);
  ktok<<<VC, 256, 0, stream>>>(embed_w, en_g, en_b, fn_g, fn_b, q_b, k_b,
                               g_w, g_b, embed_P, qk_P,
                               q_tok, kT_P, gate_tok, probs_tok);
  ktables<<<NB * VC, 256, 0, stream>>>(q_tok, kT_P, cnt, gate_tok, probs_tok,
                                       e_norm, logmix);
  kwrite<<<NB * SL, 256, 0, stream>>>(tokens, prefix_lens, e_norm, logmix,
                                      gate_tok, out_logmix, out_gate, out_attn);
}